// Round 13
// baseline (100.447 us; speedup 1.0000x reference)
//
#include <hip/hip_runtime.h>

typedef unsigned short u16;
typedef __attribute__((ext_vector_type(8))) short short8_t;   // 8 bf16 = 4 VGPRs
typedef __attribute__((ext_vector_type(4))) float f32x4;      // MFMA accumulator

#define N_SAMP 256
#define IN_F   1024
#define OUT_F  128
#define KDIM   32
#define JTOT   (OUT_F * KDIM)   // 4096
#define OUT_ROW (IN_F + OUT_F)  // 1152

#define LDBS 72   // Bs row stride (u16): 64 k + 8 pad = 144 B (16B-aligned)
#define LDMS 36   // Ms row stride (f32): 32 + 4 pad = 144 B (16B-aligned)

__device__ __forceinline__ u16 f2bf(float f) {
    union { float f; unsigned u; } v; v.f = f;
    unsigned r = v.u + 0x7FFFu + ((v.u >> 16) & 1u);   // RNE
    return (u16)(r >> 16);
}
__device__ __forceinline__ unsigned pack2(float lo, float hi) {
    return (unsigned)f2bf(lo) | ((unsigned)f2bf(hi) << 16);
}

// ===========================================================================
// MAIN PATH: conv_x -> fused_od (GEMM slice in LDS + dist, no Mt!) -> reduce2
// ===========================================================================

// --- x -> out[:, :1024] copy and x -> bf16 At[n][k] (r11-proven) ---
__global__ __launch_bounds__(256) void conv_x(const float* __restrict__ x,
                                              float* __restrict__ out,
                                              u16* __restrict__ At) {
    int n = blockIdx.x, t = threadIdx.x;
    float4 v = reinterpret_cast<const float4*>(x + (size_t)n * IN_F)[t];
    reinterpret_cast<float4*>(out + (size_t)n * OUT_ROW)[t] = v;
    ushort4 b;
    b.x = f2bf(v.x); b.y = f2bf(v.y); b.z = f2bf(v.z); b.w = f2bf(v.w);
    reinterpret_cast<ushort4*>(At + (size_t)n * IN_F)[t] = b;
}

// --- fused per-o kernel: grid 256 (o = bid>>1, mh = bid&1), 512 thr = 8 waves.
// Phase 1: Ms[256 n][32 j] = At @ T[:, o*32..o*32+32] via MFMA, Ms in LDS.
// Phase 2: pairwise exp(-L1) over (n, m in mh-half), partials to `part`.
__global__ __launch_bounds__(512) void fused_od(const u16* __restrict__ At,
                                                const float* __restrict__ T,
                                                float* __restrict__ part) {
    __shared__ u16   Bs[2][32 * LDBS];      // T-slice chunk, dbuf: 9.2 KB
    __shared__ float Ms[N_SAMP * LDMS];     // M slice [n][j]:    36.9 KB
    __shared__ float Pred[8][N_SAMP];       // per-wave partials:  8.0 KB
    const int t = threadIdx.x, w = t >> 6, l = t & 63;
    const int o  = blockIdx.x >> 1;
    const int mh = blockIdx.x & 1;
    const int jb = o * KDIM;                // T column base

    // ---------------- Phase 1: MFMA into LDS ----------------
    // T staging roles (t < 256): jt = j-quad, kp = k-pair (r12-proven pack)
    const int jt = t & 7, kp = t >> 3;
    float4 ta, tb;
    auto LOADT = [&](int c) {
        if (t < 256) {
            const int k0 = c * 64;
            ta = *reinterpret_cast<const float4*>(&T[(size_t)(k0 + 2 * kp    ) * JTOT + jb + jt * 4]);
            tb = *reinterpret_cast<const float4*>(&T[(size_t)(k0 + 2 * kp + 1) * JTOT + jb + jt * 4]);
        }
    };
    auto STORET = [&](int b) {
        if (t < 256) {
            const float* fa = reinterpret_cast<const float*>(&ta);
            const float* fb = reinterpret_cast<const float*>(&tb);
#pragma unroll
            for (int c = 0; c < 4; ++c)
                *reinterpret_cast<unsigned*>(&Bs[b][(jt * 4 + c) * LDBS + 2 * kp]) = pack2(fa[c], fb[c]);
        }
    };

    f32x4 acc[2][2];
#pragma unroll
    for (int a = 0; a < 2; ++a)
#pragma unroll
        for (int b = 0; b < 2; ++b) acc[a][b] = (f32x4){0.f, 0.f, 0.f, 0.f};

    LOADT(0); STORET(0); __syncthreads();

    for (int c = 0; c < 16; ++c) {              // 16 K-chunks of 64
        const int cur = c & 1;
        if (c < 15) LOADT(c + 1);               // next chunk's loads early
        const u16* at0 = &At[(size_t)(w * 32 +      (l & 15)) * IN_F + c * 64];
        const u16* at1 = &At[(size_t)(w * 32 + 16 + (l & 15)) * IN_F + c * 64];
#pragma unroll
        for (int s = 0; s < 2; ++s) {
            const int co = s * 32 + 8 * (l >> 4);   // same assumed k-map A and B
            short8_t a0 = *reinterpret_cast<const short8_t*>(&Bs[cur][(     (l & 15)) * LDBS + co]);
            short8_t a1 = *reinterpret_cast<const short8_t*>(&Bs[cur][(16 + (l & 15)) * LDBS + co]);
            short8_t b0 = *reinterpret_cast<const short8_t*>(&at0[co]);   // L2-hot global
            short8_t b1 = *reinterpret_cast<const short8_t*>(&at1[co]);
            acc[0][0] = __builtin_amdgcn_mfma_f32_16x16x32_bf16(a0, b0, acc[0][0], 0, 0, 0);
            acc[0][1] = __builtin_amdgcn_mfma_f32_16x16x32_bf16(a0, b1, acc[0][1], 0, 0, 0);
            acc[1][0] = __builtin_amdgcn_mfma_f32_16x16x32_bf16(a1, b0, acc[1][0], 0, 0, 0);
            acc[1][1] = __builtin_amdgcn_mfma_f32_16x16x32_bf16(a1, b1, acc[1][1], 0, 0, 0);
        }
        if (c < 15) STORET(cur ^ 1);            // write OTHER buffer
        __syncthreads();                        // single barrier per chunk
    }

    // C/D (m89-verified): col = lane&15 -> n, row = 4*(lane>>4)+reg -> j
#pragma unroll
    for (int jt2 = 0; jt2 < 2; ++jt2)
#pragma unroll
        for (int nt = 0; nt < 2; ++nt) {
            const int n  = w * 32 + nt * 16 + (l & 15);
            const int j0 = jt2 * 16 + (l >> 4) * 4;
#pragma unroll
            for (int r = 0; r < 4; ++r)
                Ms[n * LDMS + j0 + r] = acc[jt2][nt][r];
        }
    __syncthreads();

    // ---------------- Phase 2: dist (r4-proven structure) ----------------
    // lane l owns rows {l, l+64, l+128, l+192}; wave w owns 16 m's of mh-half.
    float accd[4][16];
#pragma unroll
    for (int ri = 0; ri < 4; ++ri)
#pragma unroll
        for (int mi = 0; mi < 16; ++mi) accd[ri][mi] = 0.f;

#pragma unroll
    for (int kh = 0; kh < 4; ++kh) {            // k in 4 chunks of 8
        float rr[4][8];
#pragma unroll
        for (int ri = 0; ri < 4; ++ri)
#pragma unroll
            for (int i = 0; i < 2; ++i)
                *reinterpret_cast<float4*>(&rr[ri][i * 4]) =
                    *reinterpret_cast<const float4*>(&Ms[(l + 64 * ri) * LDMS + kh * 8 + i * 4]);
#pragma unroll
        for (int mi = 0; mi < 16; ++mi) {
            const int m = mh * 128 + w * 16 + mi;
            float mo[8];
#pragma unroll
            for (int i = 0; i < 2; ++i)         // wave-uniform broadcast reads
                *reinterpret_cast<float4*>(&mo[i * 4]) =
                    *reinterpret_cast<const float4*>(&Ms[m * LDMS + kh * 8 + i * 4]);
#pragma unroll
            for (int k = 0; k < 8; ++k) {
                accd[0][mi] += fabsf(rr[0][k] - mo[k]);
                accd[1][mi] += fabsf(rr[1][k] - mo[k]);
                accd[2][mi] += fabsf(rr[2][k] - mo[k]);
                accd[3][mi] += fabsf(rr[3][k] - mo[k]);
            }
        }
    }

    float a[4] = {0.f, 0.f, 0.f, 0.f};
#pragma unroll
    for (int mi = 0; mi < 16; ++mi) {
        a[0] += __expf(-accd[0][mi]); a[1] += __expf(-accd[1][mi]);
        a[2] += __expf(-accd[2][mi]); a[3] += __expf(-accd[3][mi]);
    }
    Pred[w][l] = a[0]; Pred[w][l + 64] = a[1];
    Pred[w][l + 128] = a[2]; Pred[w][l + 192] = a[3];
    __syncthreads();

    if (t < N_SAMP) {                           // combine 8 waves' m-subranges
        float s = 0.f;
#pragma unroll
        for (int ww = 0; ww < 8; ++ww) s += Pred[ww][t];
        part[(size_t)(mh * OUT_F + o) * N_SAMP + t] = s;   // coalesced
    }
}

// --- reduce2: out[n][1024+o] = part[0][o][n] + part[1][o][n] - 1 ---
// grid 256 (n), 128 thr (o): HBM writes coalesced (512 B/block).
__global__ __launch_bounds__(128) void reduce2(const float* __restrict__ part,
                                               float* __restrict__ out) {
    const int n = blockIdx.x, o = threadIdx.x;
    float s = part[(size_t)o * N_SAMP + n]
            + part[(size_t)(OUT_F + o) * N_SAMP + n] - 1.0f;
    out[(size_t)n * OUT_ROW + IN_F + o] = s;
}

// ===========================================================================
// FALLBACK PATH (round-1 proven kernels; used only if ws is too small)
// ===========================================================================
__global__ __launch_bounds__(256) void copy_init_kernel(const float* __restrict__ x,
                                                        float* __restrict__ out) {
    int n = blockIdx.x, t = threadIdx.x;
    reinterpret_cast<float4*>(out + (size_t)n * OUT_ROW)[t] =
        reinterpret_cast<const float4*>(x + (size_t)n * IN_F)[t];
    if (t < OUT_F) out[(size_t)n * OUT_ROW + IN_F + t] = -1.0f;
}

#define BM 64
#define BN 64
#define BK 16
#define AS_STRIDE 68
__global__ __launch_bounds__(256) void gemm_kernel(const float* __restrict__ x,
                                                   const float* __restrict__ T,
                                                   float* __restrict__ M) {
    __shared__ float As_[BK][AS_STRIDE];
    __shared__ float Bs_[BK][BN];
    const int jb = blockIdx.x * BN, nb = blockIdx.y * BM;
    const int t = threadIdx.x, tx = t & 15, ty = t >> 4;
    float acc[4][4] = {};
    for (int k0 = 0; k0 < IN_F; k0 += BK) {
        {
            int row = t >> 2, cg = (t & 3) * 4;
            float4 v = *reinterpret_cast<const float4*>(&x[(size_t)(nb + row) * IN_F + k0 + cg]);
            As_[cg + 0][row] = v.x; As_[cg + 1][row] = v.y;
            As_[cg + 2][row] = v.z; As_[cg + 3][row] = v.w;
        }
        {
            int r = t >> 4, cg = (t & 15) * 4;
            *reinterpret_cast<float4*>(&Bs_[r][cg]) =
                *reinterpret_cast<const float4*>(&T[(size_t)(k0 + r) * JTOT + jb + cg]);
        }
        __syncthreads();
#pragma unroll
        for (int kk = 0; kk < BK; ++kk) {
            float4 av = *reinterpret_cast<const float4*>(&As_[kk][ty * 4]);
            float4 bv = *reinterpret_cast<const float4*>(&Bs_[kk][tx * 4]);
            float a[4] = {av.x, av.y, av.z, av.w}, b[4] = {bv.x, bv.y, bv.z, bv.w};
#pragma unroll
            for (int i = 0; i < 4; ++i)
#pragma unroll
                for (int j = 0; j < 4; ++j) acc[i][j] += a[i] * b[j];
        }
        __syncthreads();
    }
#pragma unroll
    for (int i = 0; i < 4; ++i) {
        int n = nb + ty * 4 + i;
        float4 v = make_float4(acc[i][0], acc[i][1], acc[i][2], acc[i][3]);
        *reinterpret_cast<float4*>(&M[(size_t)n * JTOT + jb + tx * 4]) = v;
    }
}

__global__ __launch_bounds__(256) void dist_kernel(const float* __restrict__ M,
                                                   float* __restrict__ out) {
    __shared__ float Mo_[64][KDIM];
    const int o = blockIdx.x >> 2, chunk = blockIdx.x & 3, t = threadIdx.x;
    float r[KDIM];
    const float4* mrow = reinterpret_cast<const float4*>(&M[(size_t)t * JTOT + o * KDIM]);
#pragma unroll
    for (int f = 0; f < 8; ++f) {
        float4 v = mrow[f];
        r[f*4+0]=v.x; r[f*4+1]=v.y; r[f*4+2]=v.z; r[f*4+3]=v.w;
    }
    const int mbase = chunk * 64;
    {
        int row = t >> 3, f4 = t & 7;
        *reinterpret_cast<float4*>(&Mo_[row][f4*4]) =
            *reinterpret_cast<const float4*>(&M[(size_t)(mbase+row)*JTOT + o*KDIM + f4*4]);
        *reinterpret_cast<float4*>(&Mo_[row+32][f4*4]) =
            *reinterpret_cast<const float4*>(&M[(size_t)(mbase+row+32)*JTOT + o*KDIM + f4*4]);
    }
    __syncthreads();
    float acc = 0.f;
    for (int m = 0; m < 64; ++m) {
        float d = 0.f;
#pragma unroll
        for (int k = 0; k < KDIM; ++k) d += fabsf(r[k] - Mo_[m][k]);
        acc += __expf(-d);
    }
    atomicAdd(&out[(size_t)t * OUT_ROW + IN_F + o], acc);
}

// ===========================================================================
extern "C" void kernel_launch(void* const* d_in, const int* in_sizes, int n_in,
                              void* d_out, int out_size, void* d_ws, size_t ws_size,
                              hipStream_t stream) {
    const float* x = (const float*)d_in[0];   // [256,1024]
    const float* T = (const float*)d_in[1];   // [1024,4096]
    float* out = (float*)d_out;               // [256,1152]

    // ws: At bf16 [256][1024] = 512 KiB | part [2*128][256] f32 = 256 KiB
    const size_t AT_BYTES = (size_t)N_SAMP * IN_F * 2;
    const size_t NEED = AT_BYTES + (size_t)2 * OUT_F * N_SAMP * 4;

    if (ws_size >= NEED) {
        u16*   At   = (u16*)d_ws;
        float* part = (float*)((char*)d_ws + AT_BYTES);

        conv_x<<<N_SAMP, 256, 0, stream>>>(x, out, At);
        fused_od<<<2 * OUT_F, 512, 0, stream>>>(At, T, part);
        reduce2<<<N_SAMP, OUT_F, 0, stream>>>(part, out);
    } else {
        float* M = (float*)d_ws;              // 4 MiB (proven available in r1)
        copy_init_kernel<<<N_SAMP, 256, 0, stream>>>(x, out);
        dim3 ggrid(JTOT / BN, N_SAMP / BM);
        gemm_kernel<<<ggrid, 256, 0, stream>>>(x, T, M);
        dist_kernel<<<OUT_F * 4, 256, 0, stream>>>(M, out);
    }
}